// Round 19
// baseline (127.279 us; speedup 1.0000x reference)
//
#include <hip/hip_runtime.h>
#include <hip/hip_bf16.h>

#define IN_FEAT 4096
#define OUT_FEAT 4096
#define FP_FEAT 256
#define INT_FEAT 3840
#define TOKENS 4096
#define PACKED_W (INT_FEAT / 2)  // 1920

#define NT_I8 60          // int K-tiles (K=64 i8 each)
#define NT_ALL 68         // + 8 fp sub-tiles (K=32 bf16 each)

typedef __attribute__((ext_vector_type(8)))  short short8;
typedef __attribute__((ext_vector_type(4)))  float f32x4;
typedef __attribute__((ext_vector_type(4)))  int   int32x4;
typedef __attribute__((ext_vector_type(16))) int   int32x16;
typedef __attribute__((ext_vector_type(16))) float f32x16;

// workspace layout (bytes)
#define AQ8_OFF   0u
#define WB8_OFF   16777216u
#define AFP_OFF   33554432u
#define WFP_OFF   35651584u
#define SCALE_OFF 37748736u
#define ZERO_OFF  37765120u
#define WS_NEED   37781504u

// ------------------------------------------------- fused quantize + unpack ---
__global__ __launch_bounds__(256) void prep_kernel(
    const float* __restrict__ x,
    const int* __restrict__ int_idx_raw,
    const int* __restrict__ fp_idx_raw,
    const int* __restrict__ wpacked_raw,
    const float* __restrict__ fpw,
    const float* __restrict__ wscale,
    signed char* __restrict__ Aq8,
    __hip_bfloat16* __restrict__ Afp,
    signed char* __restrict__ Wb8,
    __hip_bfloat16* __restrict__ Wfp,
    float* __restrict__ scale_ws,
    float* __restrict__ zero_ws)
{
    const int t = threadIdx.x;
    if (blockIdx.x < TOKENS) {
        const int m = blockIdx.x;
        const float* xr = x + (size_t)m * IN_FEAT;
        const bool is64 = (int_idx_raw[1] == 0) && (int_idx_raw[3] == 0);

        float v[15];
        float mn = 1e30f, mx = -1e30f;
#pragma unroll
        for (int j = 0; j < 15; ++j) {
            int k = t + j * 256;
            int idx = is64 ? int_idx_raw[2 * k] : int_idx_raw[k];
            float f = xr[idx];
            v[j] = f;
            mn = fminf(mn, f);
            mx = fmaxf(mx, f);
        }
#pragma unroll
        for (int off = 1; off < 64; off <<= 1) {
            mn = fminf(mn, __shfl_xor(mn, off));
            mx = fmaxf(mx, __shfl_xor(mx, off));
        }
        __shared__ float smn[4], smx[4];
        int wid = t >> 6, lane = t & 63;
        if (lane == 0) { smn[wid] = mn; smx[wid] = mx; }
        __syncthreads();
        if (t == 0) {
            float rmn = fminf(fminf(smn[0], smn[1]), fminf(smn[2], smn[3]));
            float rmx = fmaxf(fmaxf(smx[0], smx[1]), fmaxf(smx[2], smx[3]));
            float sc = fmaxf((rmx - rmn) / 15.0f, 1e-8f);
            smn[0] = rmn;
            smx[0] = sc;
            scale_ws[m] = sc;
            zero_ws[m] = rmn;
        }
        __syncthreads();
        const float zero = smn[0];
        const float sc = smx[0];

        signed char* ar = Aq8 + (size_t)m * INT_FEAT;
#pragma unroll
        for (int j = 0; j < 15; ++j) {
            int k = t + j * 256;
            float q = rintf((v[j] - zero) / sc) - 8.0f;  // IEEE div+rndne == np
            q = fminf(fmaxf(q, -8.0f), 7.0f);
            ar[k] = (signed char)(int)q;                 // exact small int
        }
        int fpi = is64 ? fp_idx_raw[2 * t] : fp_idx_raw[t];
        Afp[(size_t)m * FP_FEAT + t] = __float2bfloat16(xr[fpi] / sc);
    } else {
        const int n = blockIdx.x - TOKENS;
        bool is_i32 = true;
#pragma unroll
        for (int j = 0; j < 8; ++j) {
            unsigned w = (unsigned)wpacked_raw[j];
            if (w > 0xFFu) is_i32 = false;
        }
        short* wo = (short*)(Wb8 + (size_t)n * INT_FEAT);
#pragma unroll
        for (int j = 0; j < 8; ++j) {
            int k = t + j * 256;
            if (k < PACKED_W) {
                int p = is_i32 ? wpacked_raw[(size_t)n * PACKED_W + k]
                               : ((const unsigned char*)wpacked_raw)[(size_t)n * PACKED_W + k];
                int lo = p & 15; if (lo >= 8) lo -= 16;
                int hi = (p >> 4) & 15; if (hi >= 8) hi -= 16;
                wo[k] = (short)(((unsigned char)lo) | ((unsigned short)(unsigned char)hi << 8));
            }
        }
        float wsn = wscale[n];
        Wfp[(size_t)n * FP_FEAT + t] = __float2bfloat16(fpw[(size_t)n * FP_FEAT + t] / wsn);
    }
}

// ---------------- GEMM 256x256 i8 32x32x32 + frag prefetch + counted lgkm ---
// r19 = r18 skeleton (4 buf, stage+3, reg frag prefetch, vmcnt(4)) with:
//  * MFMA shape 32x32x32 i8 (4404 TOPS vs 3944; HALF the instructions:
//    16/wave/tile) and 32x32x16 bf16 tail (same frag geometry).
//  * explicit `s_waitcnt lgkmcnt(12)` + sched_barrier(0) before each MFMA
//    burst: exactly 12 prefetch ds_reads in flight -> proves PREVIOUS tile's
//    frags resident without draining the current prefetch (counted wait).
// Frag layout (A and B, 16B/lane): row = lane&31, k-chunk = lane>>5; LDS
// byte = row*64 + ((q ^ ((row>>1)&3))<<4), q = ks*2 + (lane>>5)  -- same
// verified swizzle family as r10-r18 (0 conflicts).
// C/D: col=lane&31, row=(reg&3)+8*(reg>>2)+4*(lane>>5) [m74/m101 verified,
// dtype-independent]. i8 math exact -> layout error shows as absmax~20.
// fp tail regrouped (K=16/instr vs 32) -> absmax may shift slightly from
// 0.1992188 (expected 0.18-0.23, threshold 0.3225); i8 path still exact.

#define PREFETCH(VT, AN, BN)                                                   \
    {                                                                          \
        const int pbB = ((VT) & 3) << 15;                                      \
        _Pragma("unroll")                                                      \
        for (int nf = 0; nf < 2; ++nf)                                         \
            _Pragma("unroll")                                                  \
            for (int ks = 0; ks < 2; ++ks)                                     \
                BN[nf][ks] = *(const int32x4*)(lds + pbB + bOff[nf][ks]);      \
        _Pragma("unroll")                                                      \
        for (int mf = 0; mf < 4; ++mf)                                         \
            _Pragma("unroll")                                                  \
            for (int ks = 0; ks < 2; ++ks)                                     \
                AN[mf][ks] = *(const int32x4*)(lds + pbB + aOff[mf][ks]);      \
    }

#define WAIT12()                                                               \
    asm volatile("s_waitcnt lgkmcnt(12)" ::: "memory");                        \
    __builtin_amdgcn_sched_barrier(0);

#define MFMA_I8(AC, BC)                                                        \
    _Pragma("unroll")                                                          \
    for (int ks = 0; ks < 2; ++ks)                                             \
        _Pragma("unroll")                                                      \
        for (int mf = 0; mf < 4; ++mf)                                         \
            _Pragma("unroll")                                                  \
            for (int nf = 0; nf < 2; ++nf)                                     \
                acc[mf][nf] = __builtin_amdgcn_mfma_i32_32x32x32_i8(           \
                    AC[mf][ks], BC[nf][ks], acc[mf][nf], 0, 0, 0);

#define MFMA_BF(AC, BC)                                                        \
    _Pragma("unroll")                                                          \
    for (int ks = 0; ks < 2; ++ks)                                             \
        _Pragma("unroll")                                                      \
        for (int mf = 0; mf < 4; ++mf)                                         \
            _Pragma("unroll")                                                  \
            for (int nf = 0; nf < 2; ++nf)                                     \
                acc[mf][nf] = __builtin_bit_cast(int32x16,                     \
                    __builtin_amdgcn_mfma_f32_32x32x16_bf16(                   \
                        __builtin_bit_cast(short8, AC[mf][ks]),                \
                        __builtin_bit_cast(short8, BC[nf][ks]),                \
                        __builtin_bit_cast(f32x16, acc[mf][nf]), 0, 0, 0));

#define ENDBAR4()                                                              \
    asm volatile("s_waitcnt vmcnt(4)" ::: "memory");                           \
    __builtin_amdgcn_sched_barrier(0);                                         \
    __builtin_amdgcn_s_barrier();                                              \
    __builtin_amdgcn_sched_barrier(0);

#define ENDBAR0()                                                              \
    asm volatile("s_waitcnt vmcnt(0)" ::: "memory");                           \
    __builtin_amdgcn_sched_barrier(0);                                         \
    __builtin_amdgcn_s_barrier();                                              \
    __builtin_amdgcn_sched_barrier(0);

#define ENDBARN()                                                              \
    __builtin_amdgcn_sched_barrier(0);                                         \
    __builtin_amdgcn_s_barrier();                                              \
    __builtin_amdgcn_sched_barrier(0);

__global__ __launch_bounds__(512, 2) void gemm256_i8(
    const signed char* __restrict__ Aq8,
    const __hip_bfloat16* __restrict__ Afp,
    const signed char* __restrict__ Wb8,
    const __hip_bfloat16* __restrict__ Wfp,
    const float* __restrict__ scale_ws,
    const float* __restrict__ zero_ws,
    const float* __restrict__ wscale,
    const float* __restrict__ reduced,
    const float* __restrict__ bias,
    float* __restrict__ out)
{
    __shared__ __align__(16) char lds[131072];  // 4 x (16K A + 16K B)

    const int t = threadIdx.x;
    const int lane = t & 63, wid = t >> 6;
    const int wr = wid >> 2;                   // 0..1
    const int wc = wid & 3;                    // 0..3
    const int r32 = lane & 31;
    const int kg2 = lane >> 5;                 // 0..1

    // XCD-aware block swizzle (256 blocks, 8 XCDs)
    const int bid = blockIdx.x;
    const int sb = (bid & 7) * 32 + (bid >> 3);
    const int tileM = (sb >> 4) * 256;
    const int tileN = (sb & 15) * 256;

    // staging geometry: identical to r10-r18 (verified, 0 conflicts)
    const int id0 = t, id1 = 512 + t;
    const int r0 = id0 >> 2, c0 = id0 & 3;
    const int r1 = id1 >> 2, c1 = id1 & 3;
    const int sw0 = ((c0 ^ ((r0 >> 1) & 3)) << 4);
    const int sw1 = ((c1 ^ ((r1 >> 1) & 3)) << 4);
    const char* a8_0 = (const char*)Aq8 + (size_t)(tileM + r0) * INT_FEAT + sw0;
    const char* a8_1 = (const char*)Aq8 + (size_t)(tileM + r1) * INT_FEAT + sw1;
    const char* b8_0 = (const char*)Wb8 + (size_t)(tileN + r0) * INT_FEAT + sw0;
    const char* b8_1 = (const char*)Wb8 + (size_t)(tileN + r1) * INT_FEAT + sw1;
    const char* af_0 = (const char*)Afp + (size_t)(tileM + r0) * 512 + sw0;
    const char* af_1 = (const char*)Afp + (size_t)(tileM + r1) * 512 + sw1;
    const char* bf_0 = (const char*)Wfp + (size_t)(tileN + r0) * 512 + sw0;
    const char* bf_1 = (const char*)Wfp + (size_t)(tileN + r1) * 512 + sw1;
    const int dst0 = id0 << 4, dst1 = id1 << 4;

    auto stage = [&](int vt, int bufB) {
        const bool i8p = vt < NT_I8;
        const int ko = i8p ? vt * 64 : (vt - NT_I8) * 64;
        const char* pa0 = (i8p ? a8_0 : af_0) + ko;
        const char* pa1 = (i8p ? a8_1 : af_1) + ko;
        const char* pb0 = (i8p ? b8_0 : bf_0) + ko;
        const char* pb1 = (i8p ? b8_1 : bf_1) + ko;
        __builtin_amdgcn_global_load_lds(
            (const __attribute__((address_space(1))) void*)pa0,
            (__attribute__((address_space(3))) void*)(lds + bufB + dst0), 16, 0, 0);
        __builtin_amdgcn_global_load_lds(
            (const __attribute__((address_space(1))) void*)pa1,
            (__attribute__((address_space(3))) void*)(lds + bufB + dst1), 16, 0, 0);
        __builtin_amdgcn_global_load_lds(
            (const __attribute__((address_space(1))) void*)pb0,
            (__attribute__((address_space(3))) void*)(lds + bufB + 16384 + dst0), 16, 0, 0);
        __builtin_amdgcn_global_load_lds(
            (const __attribute__((address_space(1))) void*)pb1,
            (__attribute__((address_space(3))) void*)(lds + bufB + 16384 + dst1), 16, 0, 0);
    };

    // fragment read byte-offsets: 64B rows, chunk q = ks*2 + kg2, swizzled
    int aOff[4][2], bOff[2][2];
#pragma unroll
    for (int mf = 0; mf < 4; ++mf)
#pragma unroll
        for (int ks = 0; ks < 2; ++ks) {
            int ra = wr * 128 + mf * 32 + r32;
            int q = ks * 2 + kg2;
            aOff[mf][ks] = ra * 64 + (((q ^ ((ra >> 1) & 3))) << 4);
        }
#pragma unroll
    for (int nf = 0; nf < 2; ++nf)
#pragma unroll
        for (int ks = 0; ks < 2; ++ks) {
            int rb = wc * 64 + nf * 32 + r32;
            int q = ks * 2 + kg2;
            bOff[nf][ks] = 16384 + rb * 64 + (((q ^ ((rb >> 1) & 3))) << 4);
        }

    int32x16 acc[4][2];
#pragma unroll
    for (int mf = 0; mf < 4; ++mf)
#pragma unroll
        for (int nf = 0; nf < 2; ++nf)
#pragma unroll
            for (int i = 0; i < 16; ++i)
                acc[mf][nf][i] = 0;

    int32x4 aP[4][2], bP[2][2], aN[4][2], bN[2][2];

    // prologue: stage 0,1,2; drain 0,1 (vmcnt(4) leaves stage(2)); barrier;
    // preload frag[0].
    stage(0, 0);
    stage(1, 32768);
    stage(2, 65536);
    asm volatile("s_waitcnt vmcnt(4)" ::: "memory");
    __builtin_amdgcn_sched_barrier(0);
    __builtin_amdgcn_s_barrier();
    __builtin_amdgcn_sched_barrier(0);
    PREFETCH(0, aP, bP);

    // ---- i8 tiles 0..57 (29 unroll-2 pairs) ----
    for (int vt = 0; vt < NT_I8 - 2; vt += 2) {
        PREFETCH(vt + 1, aN, bN);
        stage(vt + 3, ((vt + 3) & 3) << 15);
        WAIT12();
        MFMA_I8(aP, bP);
        ENDBAR4();

        PREFETCH(vt + 2, aP, bP);
        stage(vt + 4, ((vt + 4) & 3) << 15);
        WAIT12();
        MFMA_I8(aN, bN);
        ENDBAR4();
    }

    // ---- tiles 58, 59 (i8) ----
    PREFETCH(59, aN, bN);
    stage(61, (61 & 3) << 15);
    WAIT12();
    MFMA_I8(aP, bP);
    ENDBAR4();

    PREFETCH(60, aP, bP);
    stage(62, (62 & 3) << 15);
    WAIT12();
    MFMA_I8(aN, bN);
    ENDBAR4();

    // ---- exact int32 -> f32 conversion (in place) ----
#pragma unroll
    for (int mf = 0; mf < 4; ++mf)
#pragma unroll
        for (int nf = 0; nf < 2; ++nf) {
            int32x16 vi = acc[mf][nf];
            f32x16 vf;
#pragma unroll
            for (int i = 0; i < 16; ++i) vf[i] = (float)vi[i];
            acc[mf][nf] = __builtin_bit_cast(int32x16, vf);
        }

    // ---- fp tiles 60..67 (bf16 32x32x16) ----
    PREFETCH(61, aN, bN); stage(63, (63 & 3) << 15); WAIT12(); MFMA_BF(aP, bP); ENDBAR4();
    PREFETCH(62, aP, bP); stage(64, (64 & 3) << 15); WAIT12(); MFMA_BF(aN, bN); ENDBAR4();
    PREFETCH(63, aN, bN); stage(65, (65 & 3) << 15); WAIT12(); MFMA_BF(aP, bP); ENDBAR4();
    PREFETCH(64, aP, bP); stage(66, (66 & 3) << 15); WAIT12(); MFMA_BF(aN, bN); ENDBAR4();
    PREFETCH(65, aN, bN); stage(67, (67 & 3) << 15); WAIT12(); MFMA_BF(aP, bP); ENDBAR4();
    PREFETCH(66, aP, bP);                            WAIT12(); MFMA_BF(aN, bN); ENDBAR0();
    PREFETCH(67, aN, bN);                            WAIT12(); MFMA_BF(aP, bP); ENDBARN();
    MFMA_BF(aN, bN);

    // epilogue: out = sc*ws*acc + (zero + 8*sc)*reduced + bias
    // C/D 32x32: col=lane&31, row=(reg&3)+8*(reg>>2)+4*kg2
#pragma unroll
    for (int mf = 0; mf < 4; ++mf) {
#pragma unroll
        for (int nf = 0; nf < 2; ++nf) {
            int n = tileN + wc * 64 + nf * 32 + r32;
            float ws = wscale[n];
            float rd = reduced[n];
            float bs = bias[n];
            f32x16 av = __builtin_bit_cast(f32x16, acc[mf][nf]);
#pragma unroll
            for (int reg = 0; reg < 16; ++reg) {
                int row = (reg & 3) + 8 * (reg >> 2) + 4 * kg2;
                int m = tileM + wr * 128 + mf * 32 + row;
                float sc = scale_ws[m];
                float zr = zero_ws[m];
                out[(size_t)m * OUT_FEAT + n] =
                    sc * ws * av[reg]
                    + (zr + sc * 8.0f) * rd + bs;
            }
        }
    }
}

// ------------------------------------------------------------------ launch ---
extern "C" void kernel_launch(void* const* d_in, const int* in_sizes, int n_in,
                              void* d_out, int out_size, void* d_ws, size_t ws_size,
                              hipStream_t stream)
{
    const void* px = 0; const void* pw = 0; const void* pfpw = 0;
    const void* pii = 0; const void* pfi = 0;
    const void* p4096[3] = {0, 0, 0}; int n4096 = 0;
    for (int i = 0; i < n_in; ++i) {
        switch (in_sizes[i]) {
            case 16777216: px = d_in[i]; break;
            case 7864320:  pw = d_in[i]; break;
            case 1048576:  pfpw = d_in[i]; break;
            case 3840:     pii = d_in[i]; break;
            case 256:      pfi = d_in[i]; break;
            case 4096:     if (n4096 < 3) p4096[n4096++] = d_in[i]; break;
            default: break;
        }
    }
    if (!px || !pw || !pfpw || !pii || !pfi || n4096 != 3) return;

    const float* x       = (const float*)px;
    const int*   wpacked = (const int*)pw;
    const float* wscale  = (const float*)p4096[0];
    const float* reduced = (const float*)p4096[1];
    const float* bias    = (const float*)p4096[2];
    const float* fpw     = (const float*)pfpw;
    const int*   int_idx = (const int*)pii;
    const int*   fp_idx  = (const int*)pfi;
    float*       out     = (float*)d_out;

    if (ws_size < (size_t)WS_NEED) return;

    char* ws = (char*)d_ws;
    signed char*    Aq8 = (signed char*)(ws + AQ8_OFF);
    signed char*    Wb8 = (signed char*)(ws + WB8_OFF);
    __hip_bfloat16* Afp = (__hip_bfloat16*)(ws + AFP_OFF);
    __hip_bfloat16* Wfp = (__hip_bfloat16*)(ws + WFP_OFF);
    float* scale_ws     = (float*)(ws + SCALE_OFF);
    float* zero_ws      = (float*)(ws + ZERO_OFF);

    prep_kernel<<<TOKENS + OUT_FEAT, 256, 0, stream>>>(
        x, int_idx, fp_idx, wpacked, fpw, wscale,
        Aq8, Afp, Wb8, Wfp, scale_ws, zero_ws);
    gemm256_i8<<<256, 512, 0, stream>>>(Aq8, Afp, Wb8, Wfp,
                                        scale_ws, zero_ws,
                                        wscale, reduced, bias, out);
}

// Round 20
// 96.518 us; speedup vs baseline: 1.3187x; 1.3187x over previous
//
#include <hip/hip_runtime.h>
#include <hip/hip_bf16.h>

#define IN_FEAT 4096
#define OUT_FEAT 4096
#define FP_FEAT 256
#define INT_FEAT 3840
#define TOKENS 4096
#define PACKED_W (INT_FEAT / 2)  // 1920

#define NT_I8 60          // int K-tiles (K=64 i8 each)
#define NT_ALL 68         // + 8 fp sub-tiles (K=32 bf16 each)

typedef __attribute__((ext_vector_type(8))) short short8;
typedef __attribute__((ext_vector_type(4))) float f32x4;
typedef __attribute__((ext_vector_type(4))) int   int32x4;

// workspace layout (bytes)
#define AQ8_OFF   0u
#define WB8_OFF   16777216u
#define AFP_OFF   33554432u
#define WFP_OFF   35651584u
#define SCALE_OFF 37748736u
#define ZERO_OFF  37765120u
#define WS_NEED   37781504u

// ------------------------------------------------- fused quantize + unpack ---
__global__ __launch_bounds__(256) void prep_kernel(
    const float* __restrict__ x,
    const int* __restrict__ int_idx_raw,
    const int* __restrict__ fp_idx_raw,
    const int* __restrict__ wpacked_raw,
    const float* __restrict__ fpw,
    const float* __restrict__ wscale,
    signed char* __restrict__ Aq8,
    __hip_bfloat16* __restrict__ Afp,
    signed char* __restrict__ Wb8,
    __hip_bfloat16* __restrict__ Wfp,
    float* __restrict__ scale_ws,
    float* __restrict__ zero_ws)
{
    const int t = threadIdx.x;
    if (blockIdx.x < TOKENS) {
        const int m = blockIdx.x;
        const float* xr = x + (size_t)m * IN_FEAT;
        const bool is64 = (int_idx_raw[1] == 0) && (int_idx_raw[3] == 0);

        float v[15];
        float mn = 1e30f, mx = -1e30f;
#pragma unroll
        for (int j = 0; j < 15; ++j) {
            int k = t + j * 256;
            int idx = is64 ? int_idx_raw[2 * k] : int_idx_raw[k];
            float f = xr[idx];
            v[j] = f;
            mn = fminf(mn, f);
            mx = fmaxf(mx, f);
        }
#pragma unroll
        for (int off = 1; off < 64; off <<= 1) {
            mn = fminf(mn, __shfl_xor(mn, off));
            mx = fmaxf(mx, __shfl_xor(mx, off));
        }
        __shared__ float smn[4], smx[4];
        int wid = t >> 6, lane = t & 63;
        if (lane == 0) { smn[wid] = mn; smx[wid] = mx; }
        __syncthreads();
        if (t == 0) {
            float rmn = fminf(fminf(smn[0], smn[1]), fminf(smn[2], smn[3]));
            float rmx = fmaxf(fmaxf(smx[0], smx[1]), fmaxf(smx[2], smx[3]));
            float sc = fmaxf((rmx - rmn) / 15.0f, 1e-8f);
            smn[0] = rmn;
            smx[0] = sc;
            scale_ws[m] = sc;
            zero_ws[m] = rmn;
        }
        __syncthreads();
        const float zero = smn[0];
        const float sc = smx[0];

        signed char* ar = Aq8 + (size_t)m * INT_FEAT;
#pragma unroll
        for (int j = 0; j < 15; ++j) {
            int k = t + j * 256;
            float q = rintf((v[j] - zero) / sc) - 8.0f;  // IEEE div+rndne == np
            q = fminf(fmaxf(q, -8.0f), 7.0f);
            ar[k] = (signed char)(int)q;                 // exact small int
        }
        int fpi = is64 ? fp_idx_raw[2 * t] : fp_idx_raw[t];
        Afp[(size_t)m * FP_FEAT + t] = __float2bfloat16(xr[fpi] / sc);
    } else {
        const int n = blockIdx.x - TOKENS;
        bool is_i32 = true;
#pragma unroll
        for (int j = 0; j < 8; ++j) {
            unsigned w = (unsigned)wpacked_raw[j];
            if (w > 0xFFu) is_i32 = false;
        }
        short* wo = (short*)(Wb8 + (size_t)n * INT_FEAT);
#pragma unroll
        for (int j = 0; j < 8; ++j) {
            int k = t + j * 256;
            if (k < PACKED_W) {
                int p = is_i32 ? wpacked_raw[(size_t)n * PACKED_W + k]
                               : ((const unsigned char*)wpacked_raw)[(size_t)n * PACKED_W + k];
                int lo = p & 15; if (lo >= 8) lo -= 16;
                int hi = (p >> 4) & 15; if (hi >= 8) hi -= 16;
                wo[k] = (short)(((unsigned char)lo) | ((unsigned short)(unsigned char)hi << 8));
            }
        }
        float wsn = wscale[n];
        Wfp[(size_t)n * FP_FEAT + t] = __float2bfloat16(fpw[(size_t)n * FP_FEAT + t] / wsn);
    }
}

// ------------------------- GEMM 256x256 i8, register frag-prefetch pipeline --
// r20 = r18 verbatim (verified best: 96.5us total, GEMM 84-86us, 0 bank
// conflicts, MfmaUtil 35%). r19's 32x32 shape regressed (6.7M conflicts from
// the 32-row read pattern); 16x16x64 with the ((row>>1)&3) chunk swizzle is
// the conflict-free configuration.
// Pipeline: at iter t each wave (1) ds_reads frag[t+1] from buf[(t+1)&3]
// into the other reg set -- independent of (3)'s MFMA burst on frag[t], so
// the LDS port drains the prefetch during the ~1300cyc burst (ILP);
// (2) stage(t+3); (4) vmcnt(4) drains stage(t+2); (5) barrier.
// Buffer-write safety: stage(t+3)->buf[(t-1)&3]; last reads of t-1 completed
// before t-1's end barrier. K-order identical to r10-r18 -> absmax bit-exact
// 0.1992188.

#define PREFETCH(VT, AN, BN)                                                   \
    {                                                                          \
        const int pbB = ((VT) & 3) << 15;                                      \
        _Pragma("unroll")                                                      \
        for (int nf = 0; nf < 4; ++nf)                                         \
            BN[nf] = *(const int32x4*)(lds + pbB + bOff[nf]);                  \
        _Pragma("unroll")                                                      \
        for (int mf = 0; mf < 8; ++mf)                                         \
            AN[mf] = *(const int32x4*)(lds + pbB + aOff[mf]);                  \
    }

#define MFMA_I8(AC, BC)                                                        \
    _Pragma("unroll")                                                          \
    for (int mf = 0; mf < 8; ++mf)                                             \
        _Pragma("unroll")                                                      \
        for (int nf = 0; nf < 4; ++nf)                                         \
            acc[mf][nf] = __builtin_amdgcn_mfma_i32_16x16x64_i8(               \
                AC[mf], BC[nf], acc[mf][nf], 0, 0, 0);

#define MFMA_BF(AC, BC)                                                        \
    _Pragma("unroll")                                                          \
    for (int mf = 0; mf < 8; ++mf)                                             \
        _Pragma("unroll")                                                      \
        for (int nf = 0; nf < 4; ++nf)                                         \
            acc[mf][nf] = __builtin_bit_cast(int32x4,                          \
                __builtin_amdgcn_mfma_f32_16x16x32_bf16(                       \
                    __builtin_bit_cast(short8, AC[mf]),                        \
                    __builtin_bit_cast(short8, BC[nf]),                        \
                    __builtin_bit_cast(f32x4, acc[mf][nf]), 0, 0, 0));

#define ENDBAR4()                                                              \
    asm volatile("s_waitcnt vmcnt(4)" ::: "memory");                           \
    __builtin_amdgcn_sched_barrier(0);                                         \
    __builtin_amdgcn_s_barrier();                                              \
    __builtin_amdgcn_sched_barrier(0);

#define ENDBAR0()                                                              \
    asm volatile("s_waitcnt vmcnt(0)" ::: "memory");                           \
    __builtin_amdgcn_sched_barrier(0);                                         \
    __builtin_amdgcn_s_barrier();                                              \
    __builtin_amdgcn_sched_barrier(0);

#define ENDBARN()                                                              \
    __builtin_amdgcn_sched_barrier(0);                                         \
    __builtin_amdgcn_s_barrier();                                              \
    __builtin_amdgcn_sched_barrier(0);

__global__ __launch_bounds__(512, 2) void gemm256_i8(
    const signed char* __restrict__ Aq8,
    const __hip_bfloat16* __restrict__ Afp,
    const signed char* __restrict__ Wb8,
    const __hip_bfloat16* __restrict__ Wfp,
    const float* __restrict__ scale_ws,
    const float* __restrict__ zero_ws,
    const float* __restrict__ wscale,
    const float* __restrict__ reduced,
    const float* __restrict__ bias,
    float* __restrict__ out)
{
    __shared__ __align__(16) char lds[131072];  // 4 x (16K A + 16K B)

    const int t = threadIdx.x;
    const int lane = t & 63, wid = t >> 6;
    const int wr = wid >> 2;                   // 0..1
    const int wc = wid & 3;                    // 0..3
    const int r16 = lane & 15;
    const int kg = lane >> 4;                  // 0..3

    // XCD-aware block swizzle (256 blocks, 8 XCDs)
    const int bid = blockIdx.x;
    const int sb = (bid & 7) * 32 + (bid >> 3);
    const int tileM = (sb >> 4) * 256;
    const int tileN = (sb & 15) * 256;

    // staging geometry: 1024 16B-chunks per operand tile, 2 per thread
    const int id0 = t, id1 = 512 + t;
    const int r0 = id0 >> 2, c0 = id0 & 3;
    const int r1 = id1 >> 2, c1 = id1 & 3;
    const int sw0 = ((c0 ^ ((r0 >> 1) & 3)) << 4);
    const int sw1 = ((c1 ^ ((r1 >> 1) & 3)) << 4);
    const char* a8_0 = (const char*)Aq8 + (size_t)(tileM + r0) * INT_FEAT + sw0;
    const char* a8_1 = (const char*)Aq8 + (size_t)(tileM + r1) * INT_FEAT + sw1;
    const char* b8_0 = (const char*)Wb8 + (size_t)(tileN + r0) * INT_FEAT + sw0;
    const char* b8_1 = (const char*)Wb8 + (size_t)(tileN + r1) * INT_FEAT + sw1;
    const char* af_0 = (const char*)Afp + (size_t)(tileM + r0) * 512 + sw0;
    const char* af_1 = (const char*)Afp + (size_t)(tileM + r1) * 512 + sw1;
    const char* bf_0 = (const char*)Wfp + (size_t)(tileN + r0) * 512 + sw0;
    const char* bf_1 = (const char*)Wfp + (size_t)(tileN + r1) * 512 + sw1;
    const int dst0 = id0 << 4, dst1 = id1 << 4;

    auto stage = [&](int vt, int bufB) {
        const bool i8p = vt < NT_I8;
        const int ko = i8p ? vt * 64 : (vt - NT_I8) * 64;
        const char* pa0 = (i8p ? a8_0 : af_0) + ko;
        const char* pa1 = (i8p ? a8_1 : af_1) + ko;
        const char* pb0 = (i8p ? b8_0 : bf_0) + ko;
        const char* pb1 = (i8p ? b8_1 : bf_1) + ko;
        __builtin_amdgcn_global_load_lds(
            (const __attribute__((address_space(1))) void*)pa0,
            (__attribute__((address_space(3))) void*)(lds + bufB + dst0), 16, 0, 0);
        __builtin_amdgcn_global_load_lds(
            (const __attribute__((address_space(1))) void*)pa1,
            (__attribute__((address_space(3))) void*)(lds + bufB + dst1), 16, 0, 0);
        __builtin_amdgcn_global_load_lds(
            (const __attribute__((address_space(1))) void*)pb0,
            (__attribute__((address_space(3))) void*)(lds + bufB + 16384 + dst0), 16, 0, 0);
        __builtin_amdgcn_global_load_lds(
            (const __attribute__((address_space(1))) void*)pb1,
            (__attribute__((address_space(3))) void*)(lds + bufB + 16384 + dst1), 16, 0, 0);
    };

    // fragment read byte-offsets (dtype-independent: 64B rows, 16B frags)
    int aOff[8], bOff[4];
#pragma unroll
    for (int mf = 0; mf < 8; ++mf) {
        int ra = wr * 128 + mf * 16 + r16;
        aOff[mf] = ra * 64 + ((((ra >> 1) & 3) ^ kg) << 4);
    }
#pragma unroll
    for (int nf = 0; nf < 4; ++nf) {
        int rb = wc * 64 + nf * 16 + r16;
        bOff[nf] = 16384 + rb * 64 + ((((rb >> 1) & 3) ^ kg) << 4);
    }

    int32x4 acc[8][4];
#pragma unroll
    for (int mf = 0; mf < 8; ++mf)
#pragma unroll
        for (int nf = 0; nf < 4; ++nf)
            acc[mf][nf] = (int32x4){0, 0, 0, 0};

    int32x4 aP[8], bP[4], aN[8], bN[4];

    // prologue: stage tiles 0,1,2; drain 0 AND 1 (vmcnt(4) leaves stage(2));
    // barrier; preload frag[0] into P.
    stage(0, 0);
    stage(1, 32768);
    stage(2, 65536);
    asm volatile("s_waitcnt vmcnt(4)" ::: "memory");
    __builtin_amdgcn_sched_barrier(0);
    __builtin_amdgcn_s_barrier();
    __builtin_amdgcn_sched_barrier(0);
    PREFETCH(0, aP, bP);

    // ---- i8 tiles 0..57 (29 unroll-2 pairs) ----
    for (int vt = 0; vt < NT_I8 - 2; vt += 2) {
        PREFETCH(vt + 1, aN, bN);
        stage(vt + 3, ((vt + 3) & 3) << 15);
        MFMA_I8(aP, bP);
        ENDBAR4();

        PREFETCH(vt + 2, aP, bP);
        stage(vt + 4, ((vt + 4) & 3) << 15);
        MFMA_I8(aN, bN);
        ENDBAR4();
    }

    // ---- tiles 58, 59 (i8), with fp-region staging ----
    PREFETCH(59, aN, bN);
    stage(61, (61 & 3) << 15);
    MFMA_I8(aP, bP);
    ENDBAR4();

    PREFETCH(60, aP, bP);
    stage(62, (62 & 3) << 15);
    MFMA_I8(aN, bN);
    ENDBAR4();

    // ---- exact int32 -> f32 conversion (in place, bit-pattern reuse) ----
#pragma unroll
    for (int mf = 0; mf < 8; ++mf)
#pragma unroll
        for (int nf = 0; nf < 4; ++nf) {
            int32x4 vi = acc[mf][nf];
            f32x4 vf;
#pragma unroll
            for (int i = 0; i < 4; ++i) vf[i] = (float)vi[i];
            acc[mf][nf] = __builtin_bit_cast(int32x4, vf);
        }

    // ---- fp tiles 60..67 (bf16, bit-cast consumption) ----
    PREFETCH(61, aN, bN); stage(63, (63 & 3) << 15); MFMA_BF(aP, bP); ENDBAR4();
    PREFETCH(62, aP, bP); stage(64, (64 & 3) << 15); MFMA_BF(aN, bN); ENDBAR4();
    PREFETCH(63, aN, bN); stage(65, (65 & 3) << 15); MFMA_BF(aP, bP); ENDBAR4();
    PREFETCH(64, aP, bP); stage(66, (66 & 3) << 15); MFMA_BF(aN, bN); ENDBAR4();
    PREFETCH(65, aN, bN); stage(67, (67 & 3) << 15); MFMA_BF(aP, bP); ENDBAR4();
    PREFETCH(66, aP, bP);                            MFMA_BF(aN, bN); ENDBAR0();
    PREFETCH(67, aN, bN);                            MFMA_BF(aP, bP); ENDBARN();
    MFMA_BF(aN, bN);

    // epilogue: out = sc*ws*acc + (zero + 8*sc)*reduced + bias
    const int cr4 = kg * 4;
#pragma unroll
    for (int mf = 0; mf < 8; ++mf) {
#pragma unroll
        for (int nf = 0; nf < 4; ++nf) {
            int n = tileN + wc * 64 + nf * 16 + r16;
            float ws = wscale[n];
            float rd = reduced[n];
            float bs = bias[n];
            f32x4 av = __builtin_bit_cast(f32x4, acc[mf][nf]);
#pragma unroll
            for (int i = 0; i < 4; ++i) {
                int m = tileM + wr * 128 + mf * 16 + cr4 + i;
                float sc = scale_ws[m];
                float zr = zero_ws[m];
                out[(size_t)m * OUT_FEAT + n] =
                    sc * ws * av[i]
                    + (zr + sc * 8.0f) * rd + bs;
            }
        }
    }
}

// ------------------------------------------------------------------ launch ---
extern "C" void kernel_launch(void* const* d_in, const int* in_sizes, int n_in,
                              void* d_out, int out_size, void* d_ws, size_t ws_size,
                              hipStream_t stream)
{
    const void* px = 0; const void* pw = 0; const void* pfpw = 0;
    const void* pii = 0; const void* pfi = 0;
    const void* p4096[3] = {0, 0, 0}; int n4096 = 0;
    for (int i = 0; i < n_in; ++i) {
        switch (in_sizes[i]) {
            case 16777216: px = d_in[i]; break;
            case 7864320:  pw = d_in[i]; break;
            case 1048576:  pfpw = d_in[i]; break;
            case 3840:     pii = d_in[i]; break;
            case 256:      pfi = d_in[i]; break;
            case 4096:     if (n4096 < 3) p4096[n4096++] = d_in[i]; break;
            default: break;
        }
    }
    if (!px || !pw || !pfpw || !pii || !pfi || n4096 != 3) return;

    const float* x       = (const float*)px;
    const int*   wpacked = (const int*)pw;
    const float* wscale  = (const float*)p4096[0];
    const float* reduced = (const float*)p4096[1];
    const float* bias    = (const float*)p4096[2];
    const float* fpw     = (const float*)pfpw;
    const int*   int_idx = (const int*)pii;
    const int*   fp_idx  = (const int*)pfi;
    float*       out     = (float*)d_out;

    if (ws_size < (size_t)WS_NEED) return;

    char* ws = (char*)d_ws;
    signed char*    Aq8 = (signed char*)(ws + AQ8_OFF);
    signed char*    Wb8 = (signed char*)(ws + WB8_OFF);
    __hip_bfloat16* Afp = (__hip_bfloat16*)(ws + AFP_OFF);
    __hip_bfloat16* Wfp = (__hip_bfloat16*)(ws + WFP_OFF);
    float* scale_ws     = (float*)(ws + SCALE_OFF);
    float* zero_ws      = (float*)(ws + ZERO_OFF);

    prep_kernel<<<TOKENS + OUT_FEAT, 256, 0, stream>>>(
        x, int_idx, fp_idx, wpacked, fpw, wscale,
        Aq8, Afp, Wb8, Wfp, scale_ws, zero_ws);
    gemm256_i8<<<256, 512, 0, stream>>>(Aq8, Afp, Wb8, Wfp,
                                        scale_ws, zero_ws,
                                        wscale, reduced, bias, out);
}